// Round 4
// baseline (419.378 us; speedup 1.0000x reference)
//
#include <hip/hip_runtime.h>

#define KK 49        // 7*7
#define CH 128       // channels
#define NN 256       // tracks N
#define TT 16        // time
#define PITCH 68     // u32 words per row: Ps [cpair][g], D [g][ij]

typedef __attribute__((ext_vector_type(8))) short bf16x8;
typedef __attribute__((ext_vector_type(4))) float f32x4;
typedef __attribute__((ext_vector_type(4))) unsigned int u32x4;

// v_cvt_pk_bf16_f32: one VALU op converts 2 f32 -> packed 2x bf16 (RNE).
__device__ __forceinline__ unsigned int cvt_pk(float a, float b) {
    unsigned int r;
    asm("v_cvt_pk_bf16_f32 %0, %1, %2" : "=v"(r) : "v"(a), "v"(b));
    return r;
}

// One block per (level via grid.y, t, n). D-trick: D[g][ij] = fm[grid pixel g] . track[ij],
// g over the 8x8 integer pixel grid covering all bilinear corners of the 7x7 sample window.
// v4 (resubmit; round-3 bench was an infra failure, no counters): P-gather vectorized
// along x. P LDS layout transposed to [cpair j][g] (pitch 68):
//  - fast path (x-interior, ~75% of blocks, block-uniform branch): each thread owns one
//    channel-pair x two rows; loads an aligned 12-float window (3x float4) per channel/row
//    and statically selects the 8 needed pixels via uniform switch(gx0&3). 12 float4 loads
//    per thread vs 32 scalar (4x fewer scattered lane-requests), ds_write_b128 even-spread.
//  - slow path (x-border): v3 per-pixel scalar gather, column writes (bank-free).
// GEMM A-reads: 4x ds_read_b32 per fragment at (q*16+mr)%32 banks -> 2-way (free).
__global__ __launch_bounds__(256, 8) void corr_mfma_kernel(
    const float* __restrict__ fm0, const float* __restrict__ tk0,
    const float* __restrict__ fm1, const float* __restrict__ tk1,
    const float* __restrict__ fm2, const float* __restrict__ tk2,
    const float* __restrict__ fm3, const float* __restrict__ tk3,
    const float* __restrict__ coords, float* __restrict__ out)
{
    const int lvl = blockIdx.y;
    const float* fm  = lvl == 0 ? fm0 : lvl == 1 ? fm1 : lvl == 2 ? fm2 : fm3;
    const float* trk = lvl == 0 ? tk0 : lvl == 1 ? tk1 : lvl == 2 ? tk2 : tk3;
    const int H = 96 >> lvl, W = 128 >> lvl;
    const float inv = 1.0f / (float)(1 << lvl);

    // Ps: bf16-pairs [64 cpair][PITCH] (17408 B) -> reused as D: f32 [64 g][PITCH]
    __shared__ unsigned int smemPD[64 * PITCH];
    __shared__ int   rowoff[KK];             // (iy*8+ix)*PITCH per sample point
    __shared__ float wxs[KK], wys[KK];       // bilinear weights

    const int tid  = threadIdx.x;
    const int wave = tid >> 6;
    const int lane = tid & 63;
    const int t = blockIdx.x >> 8;
    const int n = blockIdx.x & 255;

    const int mr = lane & 15;
    const int q  = lane >> 4;

    // ---- B loads first: independent of coords, deepest latency to hide ----
    const int ij = min(wave * 16 + mr, KK - 1);
    const float* tb = trk + (size_t)ij * (NN * CH) + (size_t)n * CH + q * 8;
    f32x4 bl[4], bh[4];
    #pragma unroll
    for (int ks = 0; ks < 4; ++ks) {
        bl[ks] = *(const f32x4*)(tb + ks * 32);
        bh[ks] = *(const f32x4*)(tb + ks * 32 + 4);
    }

    // coords broadcast to all threads
    const float2 c2 = *(const float2*)(coords + (size_t)(t * NN + n) * 2);
    const float cx = c2.x * inv;
    const float cy = c2.y * inv;
    const int gx0 = (int)floorf(cx) - 3;
    const int gy0 = (int)floorf(cy) - 3;

    // ---- Phase A: interp tables (VALU work overlapping B-load latency) ----
    if (tid < KK) {
        const int h = tid / 7;            // x-offset index
        const int w = tid - h * 7;        // y-offset index
        float x = fminf(fmaxf(cx + (float)(h - 3), 0.0f), (float)(W - 1));
        float y = fminf(fmaxf(cy + (float)(w - 3), 0.0f), (float)(H - 1));
        const float x0 = floorf(x), y0 = floorf(y);
        wxs[tid] = x - x0;
        wys[tid] = y - y0;
        const int ix = min(max((int)x0 - gx0, 0), 6);
        const int iy = min(max((int)y0 - gy0, 0), 6);
        rowoff[tid] = (iy * 8 + ix) * PITCH;
    }

    // ---- convert B to bf16 fragments: word w = channels (2*(ks*16+q*4+w), +1) ----
    bf16x8 bfrag[4];
    #pragma unroll
    for (int ks = 0; ks < 4; ++ks) {
        union { bf16x8 v; u32x4 u; } bu;
        bu.u[0] = cvt_pk(bl[ks][0], bl[ks][1]);
        bu.u[1] = cvt_pk(bl[ks][2], bl[ks][3]);
        bu.u[2] = cvt_pk(bh[ks][0], bh[ks][1]);
        bu.u[3] = cvt_pk(bh[ks][2], bh[ks][3]);
        bfrag[ks] = bu.v;
    }

    // ---- P staging into Ps[cpair j][g], g = row*8 + slot, pixel(slot) = gx0+slot ----
    {
        const int HW = H * W;
        const float* fmt = fm + (size_t)t * CH * HW;
        const int xal = gx0 & ~3;
        if (xal >= 0 && xal + 11 <= W - 1) {
            // fast path: thread owns cpair jj = tid>>2, rows r0, r0+1
            const int s  = gx0 & 3;              // block-uniform shift
            const int jj = tid >> 2;
            const int c0 = 2 * jj;
            const int r0 = (tid & 3) * 2;
            #pragma unroll
            for (int rr = 0; rr < 2; ++rr) {
                const int r  = r0 + rr;
                const int py = min(max(gy0 + r, 0), H - 1);
                const float* rp0 = fmt + (size_t)c0 * HW + (size_t)py * W + xal;
                const float* rp1 = rp0 + HW;     // channel c0+1
                union { f32x4 v[3]; float f[12]; } A, B;
                A.v[0] = *(const f32x4*)(rp0);
                A.v[1] = *(const f32x4*)(rp0 + 4);
                A.v[2] = *(const f32x4*)(rp0 + 8);
                B.v[0] = *(const f32x4*)(rp1);
                B.v[1] = *(const f32x4*)(rp1 + 4);
                B.v[2] = *(const f32x4*)(rp1 + 8);
                u32x4 w0, w1;
#define PACKCASE(S) \
                w0[0] = cvt_pk(A.f[S+0], B.f[S+0]); \
                w0[1] = cvt_pk(A.f[S+1], B.f[S+1]); \
                w0[2] = cvt_pk(A.f[S+2], B.f[S+2]); \
                w0[3] = cvt_pk(A.f[S+3], B.f[S+3]); \
                w1[0] = cvt_pk(A.f[S+4], B.f[S+4]); \
                w1[1] = cvt_pk(A.f[S+5], B.f[S+5]); \
                w1[2] = cvt_pk(A.f[S+6], B.f[S+6]); \
                w1[3] = cvt_pk(A.f[S+7], B.f[S+7]); break;
                switch (s) {
                    case 0:  PACKCASE(0)
                    case 1:  PACKCASE(1)
                    case 2:  PACKCASE(2)
                    default: PACKCASE(3)
                }
#undef PACKCASE
                *(u32x4*)&smemPD[jj * PITCH + r * 8]     = w0;
                *(u32x4*)&smemPD[jj * PITCH + r * 8 + 4] = w1;
            }
        } else {
            // slow path: per-pixel scalar gather (x-border blocks), transposed writes
            const int py = min(max(gy0 + (lane >> 3), 0), H - 1);
            const int px = min(max(gx0 + (lane & 7), 0), W - 1);
            const float* base = fmt + (size_t)py * W + px;
            #pragma unroll 4
            for (int jb = wave * 16; jb < wave * 16 + 16; ++jb) {
                const float a0 = base[(size_t)(2 * jb) * HW];
                const float a1 = base[(size_t)(2 * jb + 1) * HW];
                smemPD[jb * PITCH + lane] = cvt_pk(a0, a1);   // 64 contiguous words/instr
            }
        }
    }
    __syncthreads();

    // ---- GEMM: D[64 g][64 ij] = P(64x128) x Tr^T(128x64), per-wave 16-col strip ----
    f32x4 acc[4];
    #pragma unroll
    for (int m = 0; m < 4; ++m) acc[m] = (f32x4){0.f, 0.f, 0.f, 0.f};
    {
        #pragma unroll
        for (int ks = 0; ks < 4; ++ks) {
            const int jb = ks * 16 + q * 4;
            #pragma unroll
            for (int m = 0; m < 4; ++m) {
                const int g = m * 16 + mr;
                union { bf16x8 v; unsigned int u[4]; } au;
                au.u[0] = smemPD[(jb + 0) * PITCH + g];
                au.u[1] = smemPD[(jb + 1) * PITCH + g];
                au.u[2] = smemPD[(jb + 2) * PITCH + g];
                au.u[3] = smemPD[(jb + 3) * PITCH + g];
                acc[m] = __builtin_amdgcn_mfma_f32_16x16x32_bf16(au.v, bfrag[ks], acc[m], 0, 0, 0);
            }
        }
    }
    __syncthreads();   // all waves done reading Ps before overwriting with D

    // ---- Spill D (C/D layout: col=lane&15, row=quad*4+reg) ----
    {
        float* D = (float*)smemPD;   // [g][ij], pitch PITCH
        const int col = wave * 16 + mr;
        #pragma unroll
        for (int m = 0; m < 4; ++m) {
            #pragma unroll
            for (int r = 0; r < 4; ++r) {
                D[(m * 16 + q * 4 + r) * PITCH + col] = acc[m][r];
            }
        }
    }
    __syncthreads();

    // ---- Interp + store: out[p][ij] = bilinear of 4 D rows ----
    {
        const float* D = (const float*)smemPD;
        float* op = out + (((size_t)lvl * TT + t) * NN + n) * (KK * KK);
        for (int idx = tid; idx < KK * KK; idx += 256) {
            const int p   = idx / KK;
            const int ijc = idx - p * KK;
            const float wx = wxs[p], wy = wys[p];
            const float* d0 = &D[rowoff[p] + ijc];
            const float v00 = d0[0];
            const float v01 = d0[PITCH];          // gx+1
            const float v10 = d0[8 * PITCH];      // gy+1
            const float v11 = d0[9 * PITCH];
            op[idx] = v00 * (1.f - wy) * (1.f - wx) + v01 * (1.f - wy) * wx
                    + v10 * wy * (1.f - wx)       + v11 * wy * wx;
        }
    }
}

extern "C" void kernel_launch(void* const* d_in, const int* in_sizes, int n_in,
                              void* d_out, int out_size, void* d_ws, size_t ws_size,
                              hipStream_t stream) {
    // setup_inputs() dict order (interleaved): fmaps0, track0, fmaps1, track1,
    // fmaps2, track2, fmaps3, track3, coords
    hipLaunchKernelGGL(corr_mfma_kernel, dim3(TT * NN, 4), dim3(256), 0, stream,
                       (const float*)d_in[0], (const float*)d_in[1],
                       (const float*)d_in[2], (const float*)d_in[3],
                       (const float*)d_in[4], (const float*)d_in[5],
                       (const float*)d_in[6], (const float*)d_in[7],
                       (const float*)d_in[8], (float*)d_out);
}

// Round 5
// 338.369 us; speedup vs baseline: 1.2394x; 1.2394x over previous
//
#include <hip/hip_runtime.h>

#define KK 49        // 7*7
#define CH 128       // channels
#define NN 256       // tracks N
#define TT 16        // time
#define PITCH 68     // u32 words per row of D [g][ij]

// workspace layout (u32 words)
#define FMB0_OFF 0u
#define FMB1_OFF 12582912u            // + 16*96*128*64
#define FMB2_OFF 15728640u            // + 16*48*64*64
#define FMB3_OFF 16515072u            // + 16*24*32*64
#define TKB_OFF  16711680u            // + 16*12*16*64
#define TK_WORDS 802816u              // 49*256*128/2 per level
#define WS_NEEDED 79691776ull         // (TKB_OFF + 4*TK_WORDS)*4 bytes

typedef __attribute__((ext_vector_type(8))) short bf16x8;
typedef __attribute__((ext_vector_type(4))) float f32x4;
typedef __attribute__((ext_vector_type(4))) unsigned int u32x4;

__device__ __forceinline__ unsigned int cvt_pk(float a, float b) {
    unsigned int r;
    asm("v_cvt_pk_bf16_f32 %0, %1, %2" : "=v"(r) : "v"(a), "v"(b));
    return r;
}

// ---------------- pre-pass 1: fmaps NCHW f32 -> NHWC bf16 (u32-packed pairs) ----------
// block = one (t, y) row of one level; LDS-transposed so both global reads (x-contig per
// channel) and global writes (c-contig per pixel, 1KB/wave) are coalesced.
__global__ void fm_prepass(
    const float* __restrict__ fm0, const float* __restrict__ fm1,
    const float* __restrict__ fm2, const float* __restrict__ fm3,
    unsigned int* __restrict__ ws)
{
    const int lvl = blockIdx.y;
    const float* fm = lvl == 0 ? fm0 : lvl == 1 ? fm1 : lvl == 2 ? fm2 : fm3;
    unsigned int* dstl = ws + (lvl == 0 ? FMB0_OFF : lvl == 1 ? FMB1_OFF :
                               lvl == 2 ? FMB2_OFF : FMB3_OFF);
    const int H = 96 >> lvl, W = 128 >> lvl;
    const int bx = blockIdx.x;
    if (bx >= TT * H) return;
    const int t = bx / H;
    const int y = bx - t * H;
    const int tid = threadIdx.x;

    const float* src = fm + ((size_t)t * CH * H + y) * W;       // + c*H*W + x
    unsigned int* dst = dstl + ((size_t)(t * H + y) * W) * 64;  // + x*64 + c/2

    __shared__ unsigned int Tt[16 * 68];   // [16 x][64 cpair + pad]

    const int ntile = W >> 4;
    for (int xt = 0; xt < ntile; ++xt) {
        // load + convert: cp = it*16 + tid>>4, x = tid&15 (x-contiguous reads per channel)
        #pragma unroll
        for (int it = 0; it < 4; ++it) {
            const int cp = it * 16 + (tid >> 4);
            const int x  = tid & 15;
            const float f0 = src[(size_t)(2 * cp)     * H * W + xt * 16 + x];
            const float f1 = src[(size_t)(2 * cp + 1) * H * W + xt * 16 + x];
            Tt[x * 68 + cp] = cvt_pk(f0, f1);
        }
        __syncthreads();
        // store: x = tid>>4, ct = tid&15 -> 16 px x 256B, 1KB contiguous per wave
        {
            const int x = tid >> 4, ct = tid & 15;
            const u32x4 v = *(const u32x4*)&Tt[x * 68 + ct * 4];
            *(u32x4*)&dst[(size_t)(xt * 16 + x) * 64 + ct * 4] = v;
        }
        __syncthreads();
    }
}

// ---------------- pre-pass 2: tracks f32 -> bf16 (same layout, packed pairs) ----------
__global__ void tk_prepass(
    const float* __restrict__ tk0, const float* __restrict__ tk1,
    const float* __restrict__ tk2, const float* __restrict__ tk3,
    unsigned int* __restrict__ ws)
{
    const int lvl = blockIdx.y;
    const float* src = lvl == 0 ? tk0 : lvl == 1 ? tk1 : lvl == 2 ? tk2 : tk3;
    const unsigned int idx = blockIdx.x * 256 + threadIdx.x;   // grid.x*256 == TK_WORDS
    const float2 v = ((const float2*)src)[idx];
    ws[TKB_OFF + (size_t)lvl * TK_WORDS + idx] = cvt_pk(v.x, v.y);
}

// ---------------- main kernel v5: NHWC-bf16 gather via global_load_lds ----------------
// D-trick as before. P staging: per wave 4x global_load_lds dwordx4 (1KB each, 4 pixels'
// full 256B records, contiguous along x). LDS dest linear; per-lane GLOBAL source chunk
// pre-swizzled (c4 ^ (g&7)) so the swizzled ds_read_b128 A-fragment reads are bank-uniform
// (m173 pattern: both-sides-or-neither). B fragments load bf16 directly, zero conversion.
__global__ __launch_bounds__(256, 8) void corr_mfma_v5(
    const unsigned int* __restrict__ ws,
    const float* __restrict__ coords, float* __restrict__ out)
{
    const int lvl = blockIdx.y;
    const unsigned int* fmb = ws + (lvl == 0 ? FMB0_OFF : lvl == 1 ? FMB1_OFF :
                                    lvl == 2 ? FMB2_OFF : FMB3_OFF);
    const unsigned int* tkb = ws + TKB_OFF + (size_t)lvl * TK_WORDS;
    const int H = 96 >> lvl, W = 128 >> lvl;
    const float inv = 1.0f / (float)(1 << lvl);

    // P: bf16 [64 g][64 u32, stride 64] (16KB) -> reused as D: f32 [64 g][PITCH]
    __shared__ unsigned int smemPD[64 * PITCH];
    __shared__ int   rowoff[KK];
    __shared__ float wxs[KK], wys[KK];

    const int tid  = threadIdx.x;
    const int wave = tid >> 6;
    const int lane = tid & 63;
    const int t = blockIdx.x >> 8;
    const int n = blockIdx.x & 255;
    const int mr = lane & 15;
    const int q  = lane >> 4;

    // ---- B fragments: direct bf16 loads, issued first ----
    const int ij = min(wave * 16 + mr, KK - 1);
    const unsigned int* tb = tkb + ((size_t)(ij * NN + n) << 6) + (q << 2);
    u32x4 braw[4];
    #pragma unroll
    for (int ks = 0; ks < 4; ++ks) braw[ks] = *(const u32x4*)(tb + (ks << 4));

    // coords broadcast
    const float2 c2 = *(const float2*)(coords + (size_t)(t * NN + n) * 2);
    const float cx = c2.x * inv;
    const float cy = c2.y * inv;
    const int gx0 = (int)floorf(cx) - 3;
    const int gy0 = (int)floorf(cy) - 3;

    // ---- interp tables ----
    if (tid < KK) {
        const int h = tid / 7;
        const int w = tid - h * 7;
        float x = fminf(fmaxf(cx + (float)(h - 3), 0.0f), (float)(W - 1));
        float y = fminf(fmaxf(cy + (float)(w - 3), 0.0f), (float)(H - 1));
        const float x0 = floorf(x), y0 = floorf(y);
        wxs[tid] = x - x0;
        wys[tid] = y - y0;
        const int ix = min(max((int)x0 - gx0, 0), 6);
        const int iy = min(max((int)y0 - gy0, 0), 6);
        rowoff[tid] = (iy * 8 + ix) * PITCH;
    }

    // ---- P staging: wave w stages rows [16w,16w+16), 4 pixels per instr ----
    {
        const unsigned int* fmt = fmb + (size_t)t * (H * W * 64);
        #pragma unroll
        for (int it = 0; it < 4; ++it) {
            const int g  = wave * 16 + it * 4 + (lane >> 4);
            const int py = min(max(gy0 + (g >> 3), 0), H - 1);
            const int px = min(max(gx0 + (g & 7), 0), W - 1);
            const int c4 = lane & 15;
            const unsigned int* src = fmt + ((size_t)(py * W + px) << 6)
                                          + ((c4 ^ (g & 7)) << 2);   // pre-swizzled source
            unsigned int* dst = &smemPD[(wave * 16 + it * 4) << 6];  // wave-uniform, linear
            __builtin_amdgcn_global_load_lds(
                (const __attribute__((address_space(1))) unsigned int*)src,
                (__attribute__((address_space(3))) unsigned int*)dst, 16, 0, 0);
        }
    }
    __syncthreads();

    // ---- GEMM: D[64 g][64 ij] = P(64x128) x Tr^T(128x64) ----
    f32x4 acc[4];
    #pragma unroll
    for (int m = 0; m < 4; ++m) acc[m] = (f32x4){0.f, 0.f, 0.f, 0.f};
    {
        #pragma unroll
        for (int ks = 0; ks < 4; ++ks) {
            union { bf16x8 v; u32x4 u; } bu; bu.u = braw[ks];
            #pragma unroll
            for (int m = 0; m < 4; ++m) {
                const int g = m * 16 + mr;
                union { bf16x8 v; u32x4 u; } au;
                au.u = *(const u32x4*)&smemPD[(g << 6) + ((((ks << 2) + q) ^ (g & 7)) << 2)];
                acc[m] = __builtin_amdgcn_mfma_f32_16x16x32_bf16(au.v, bu.v, acc[m], 0, 0, 0);
            }
        }
    }
    __syncthreads();

    // ---- Spill D (C/D layout: col=lane&15, row=quad*4+reg) ----
    {
        float* D = (float*)smemPD;
        const int col = wave * 16 + mr;
        #pragma unroll
        for (int m = 0; m < 4; ++m) {
            #pragma unroll
            for (int r = 0; r < 4; ++r) {
                D[(m * 16 + q * 4 + r) * PITCH + col] = acc[m][r];
            }
        }
    }
    __syncthreads();

    // ---- Interp + store ----
    {
        const float* D = (const float*)smemPD;
        float* op = out + (((size_t)lvl * TT + t) * NN + n) * (KK * KK);
        for (int idx = tid; idx < KK * KK; idx += 256) {
            const int p   = idx / KK;
            const int ijc = idx - p * KK;
            const float wx = wxs[p], wy = wys[p];
            const float* d0 = &D[rowoff[p] + ijc];
            const float v00 = d0[0];
            const float v01 = d0[PITCH];
            const float v10 = d0[8 * PITCH];
            const float v11 = d0[9 * PITCH];
            op[idx] = v00 * (1.f - wy) * (1.f - wx) + v01 * (1.f - wy) * wx
                    + v10 * wy * (1.f - wx)       + v11 * wy * wx;
        }
    }
}

// ---------------- fallback (v3, known-good) if workspace too small ----------------
__device__ __forceinline__ unsigned int f2bf(float f) {
    unsigned int u = __float_as_uint(f);
    return (u + 0x7fffu + ((u >> 16) & 1u)) >> 16;
}

__global__ __launch_bounds__(256, 8) void corr_mfma_fallback(
    const float* __restrict__ fm0, const float* __restrict__ tk0,
    const float* __restrict__ fm1, const float* __restrict__ tk1,
    const float* __restrict__ fm2, const float* __restrict__ tk2,
    const float* __restrict__ fm3, const float* __restrict__ tk3,
    const float* __restrict__ coords, float* __restrict__ out)
{
    const int lvl = blockIdx.y;
    const float* fm  = lvl == 0 ? fm0 : lvl == 1 ? fm1 : lvl == 2 ? fm2 : fm3;
    const float* trk = lvl == 0 ? tk0 : lvl == 1 ? tk1 : lvl == 2 ? tk2 : tk3;
    const int H = 96 >> lvl, W = 128 >> lvl;
    const float inv = 1.0f / (float)(1 << lvl);

    __shared__ unsigned int smemPD[64 * PITCH];
    __shared__ int   rowoff[KK];
    __shared__ float wxs[KK], wys[KK];

    const int tid  = threadIdx.x;
    const int wave = tid >> 6;
    const int lane = tid & 63;
    const int t = blockIdx.x >> 8;
    const int n = blockIdx.x & 255;
    const int mr = lane & 15;
    const int q  = lane >> 4;

    const int ij = min(wave * 16 + mr, KK - 1);
    const float* tb = trk + (size_t)ij * (NN * CH) + (size_t)n * CH + q * 8;
    f32x4 bl[4], bh[4];
    #pragma unroll
    for (int ks = 0; ks < 4; ++ks) {
        bl[ks] = *(const f32x4*)(tb + ks * 32);
        bh[ks] = *(const f32x4*)(tb + ks * 32 + 4);
    }

    const float2 c2 = *(const float2*)(coords + (size_t)(t * NN + n) * 2);
    const float cx = c2.x * inv;
    const float cy = c2.y * inv;
    const int gx0 = (int)floorf(cx) - 3;
    const int gy0 = (int)floorf(cy) - 3;

    if (tid < KK) {
        const int h = tid / 7;
        const int w = tid - h * 7;
        float x = fminf(fmaxf(cx + (float)(h - 3), 0.0f), (float)(W - 1));
        float y = fminf(fmaxf(cy + (float)(w - 3), 0.0f), (float)(H - 1));
        const float x0 = floorf(x), y0 = floorf(y);
        wxs[tid] = x - x0;
        wys[tid] = y - y0;
        const int ix = min(max((int)x0 - gx0, 0), 6);
        const int iy = min(max((int)y0 - gy0, 0), 6);
        rowoff[tid] = (iy * 8 + ix) * PITCH;
    }

    bf16x8 bfrag[4];
    #pragma unroll
    for (int ks = 0; ks < 4; ++ks) {
        union { bf16x8 v; u32x4 u; } bu;
        bu.u[0] = cvt_pk(bl[ks][0], bl[ks][1]);
        bu.u[1] = cvt_pk(bl[ks][2], bl[ks][3]);
        bu.u[2] = cvt_pk(bh[ks][0], bh[ks][1]);
        bu.u[3] = cvt_pk(bh[ks][2], bh[ks][3]);
        bfrag[ks] = bu.v;
    }

    {
        const int HW = H * W;
        const int py = min(max(gy0 + (lane >> 3), 0), H - 1);
        const int px = min(max(gx0 + (lane & 7), 0), W - 1);
        const float* base = fm + (size_t)t * CH * HW + (size_t)py * W + px;
        const int j0 = wave * 16;
        #pragma unroll
        for (int c4 = 0; c4 < 4; ++c4) {
            const int jb = j0 + c4 * 4;
            float a[8];
            #pragma unroll
            for (int i = 0; i < 8; ++i)
                a[i] = base[(size_t)(2 * jb + i) * HW];
            u32x4 wv;
            wv[0] = cvt_pk(a[0], a[1]);
            wv[1] = cvt_pk(a[2], a[3]);
            wv[2] = cvt_pk(a[4], a[5]);
            wv[3] = cvt_pk(a[6], a[7]);
            *(u32x4*)&smemPD[lane * PITCH + jb] = wv;
        }
    }
    __syncthreads();

    f32x4 acc[4];
    #pragma unroll
    for (int m = 0; m < 4; ++m) acc[m] = (f32x4){0.f, 0.f, 0.f, 0.f};
    {
        const unsigned short* P = (const unsigned short*)smemPD;  // pitch 136 shorts
        #pragma unroll
        for (int ks = 0; ks < 4; ++ks) {
            const int kof = ks * 32 + q * 8;
            #pragma unroll
            for (int m = 0; m < 4; ++m) {
                const bf16x8 a = *(const bf16x8*)&P[(m * 16 + mr) * 136 + kof];
                acc[m] = __builtin_amdgcn_mfma_f32_16x16x32_bf16(a, bfrag[ks], acc[m], 0, 0, 0);
            }
        }
    }
    __syncthreads();

    {
        float* D = (float*)smemPD;
        const int col = wave * 16 + mr;
        #pragma unroll
        for (int m = 0; m < 4; ++m) {
            #pragma unroll
            for (int r = 0; r < 4; ++r) {
                D[(m * 16 + q * 4 + r) * PITCH + col] = acc[m][r];
            }
        }
    }
    __syncthreads();

    {
        const float* D = (const float*)smemPD;
        float* op = out + (((size_t)lvl * TT + t) * NN + n) * (KK * KK);
        for (int idx = tid; idx < KK * KK; idx += 256) {
            const int p   = idx / KK;
            const int ijc = idx - p * KK;
            const float wx = wxs[p], wy = wys[p];
            const float* d0 = &D[rowoff[p] + ijc];
            const float v00 = d0[0];
            const float v01 = d0[PITCH];
            const float v10 = d0[8 * PITCH];
            const float v11 = d0[9 * PITCH];
            op[idx] = v00 * (1.f - wy) * (1.f - wx) + v01 * (1.f - wy) * wx
                    + v10 * wy * (1.f - wx)       + v11 * wy * wx;
        }
    }
}

extern "C" void kernel_launch(void* const* d_in, const int* in_sizes, int n_in,
                              void* d_out, int out_size, void* d_ws, size_t ws_size,
                              hipStream_t stream) {
    // setup_inputs() dict order (interleaved): fmaps0, track0, fmaps1, track1,
    // fmaps2, track2, fmaps3, track3, coords
    if (ws_size < WS_NEEDED || d_ws == nullptr) {
        hipLaunchKernelGGL(corr_mfma_fallback, dim3(TT * NN, 4), dim3(256), 0, stream,
                           (const float*)d_in[0], (const float*)d_in[1],
                           (const float*)d_in[2], (const float*)d_in[3],
                           (const float*)d_in[4], (const float*)d_in[5],
                           (const float*)d_in[6], (const float*)d_in[7],
                           (const float*)d_in[8], (float*)d_out);
        return;
    }
    unsigned int* ws = (unsigned int*)d_ws;
    hipLaunchKernelGGL(fm_prepass, dim3(TT * 96, 4), dim3(256), 0, stream,
                       (const float*)d_in[0], (const float*)d_in[2],
                       (const float*)d_in[4], (const float*)d_in[6], ws);
    hipLaunchKernelGGL(tk_prepass, dim3(TK_WORDS / 256, 4), dim3(256), 0, stream,
                       (const float*)d_in[1], (const float*)d_in[3],
                       (const float*)d_in[5], (const float*)d_in[7], ws);
    hipLaunchKernelGGL(corr_mfma_v5, dim3(TT * NN, 4), dim3(256), 0, stream,
                       (const unsigned int*)ws, (const float*)d_in[8], (float*)d_out);
}